// Round 1
// baseline (486.004 us; speedup 1.0000x reference)
//
#include <hip/hip_runtime.h>

#define NEG_INF_F (-4294967295.0f)

typedef __attribute__((ext_vector_type(8))) __bf16 bf16x8;
typedef __attribute__((ext_vector_type(4))) float f32x4;

__device__ __forceinline__ unsigned short f2bf(float f) {
  return __builtin_bit_cast(unsigned short, (__bf16)f);
}
__device__ __forceinline__ f32x4 mfma16(bf16x8 a, bf16x8 b, f32x4 c) {
  return __builtin_amdgcn_mfma_f32_16x16x32_bf16(a, b, c, 0, 0, 0);
}
__device__ __forceinline__ bf16x8 ld_bf8(const unsigned short* p) {
  return *(const bf16x8*)p;
}

// ---------------------------------------------------------------------------
// Kernel 1: transpose + convert the three 512x512 weight matrices to bf16,
// layout Wt[z][n][k] (n-major) so MFMA B-fragments read contiguous k.
// ---------------------------------------------------------------------------
__global__ __launch_bounds__(256) void wt_kernel(const float* __restrict__ Wq,
                                                 const float* __restrict__ Wk,
                                                 const float* __restrict__ Wv,
                                                 unsigned short* __restrict__ Wt) {
  int idx = blockIdx.x * 256 + threadIdx.x;
  int o = idx * 8;                  // output element index, 3*512*512 total
  int z = o >> 18;                  // 512*512 = 262144
  int rem = o & 262143;
  int n = rem >> 9;
  int k0 = rem & 511;
  const float* W = (z == 0) ? Wq : ((z == 1) ? Wk : Wv);
  unsigned int w[4];
#pragma unroll
  for (int i = 0; i < 4; ++i) {
    unsigned short lo = f2bf(W[(k0 + 2 * i) * 512 + n]);
    unsigned short hi = f2bf(W[(k0 + 2 * i + 1) * 512 + n]);
    w[i] = (unsigned)lo | ((unsigned)hi << 16);
  }
  *(uint4*)(Wt + o) = make_uint4(w[0], w[1], w[2], w[3]);
}

// ---------------------------------------------------------------------------
// Kernel 2: key/query padding masks: sign(|row sum|) of the RAW inputs.
// One wave per row; 16384 rows total (first 8192 = queries, rest = keys).
// ---------------------------------------------------------------------------
__global__ __launch_bounds__(256) void mask_kernel(const float* __restrict__ q,
                                                   const float* __restrict__ k,
                                                   float* __restrict__ qmask,
                                                   float* __restrict__ kmask) {
  int w = blockIdx.x * 4 + (threadIdx.x >> 6);
  int lane = threadIdx.x & 63;
  const float* src = (w < 8192) ? q : k;
  int row = w & 8191;
  const float4* p = (const float4*)(src + row * 512);
  float4 v1 = p[lane];
  float4 v2 = p[64 + lane];
  float s = v1.x + v1.y + v1.z + v1.w + v2.x + v2.y + v2.z + v2.w;
#pragma unroll
  for (int off = 32; off > 0; off >>= 1) s += __shfl_xor(s, off);
  if (lane == 0) {
    float m = (s == 0.0f) ? 0.0f : 1.0f;
    if (w < 8192) qmask[row] = m; else kmask[row] = m;
  }
}

// ---------------------------------------------------------------------------
// Kernel 3: QKV projection.  C[8192,512] = relu(X @ W + b) in bf16.
// Block = 64x64 tile (4 waves x 16 rows), K-loop 16 x BK32, mfma 16x16x32.
// z==2 (V) is written transposed per head: Vt[(h*4+b)*64 + j][t]  (bf16).
// ---------------------------------------------------------------------------
__global__ __launch_bounds__(256) void proj_kernel(
    const float* __restrict__ Xq, const float* __restrict__ Xk,
    const float* __restrict__ Xv, const float* __restrict__ bq,
    const float* __restrict__ bk, const float* __restrict__ bv,
    const unsigned short* __restrict__ Wt, unsigned short* __restrict__ Qb,
    unsigned short* __restrict__ Kb, unsigned short* __restrict__ Vt) {
  __shared__ unsigned short vlds[64 * 72];  // +8 pad per row: bank-conflict-free transpose
  int z = blockIdx.z;
  const float* X = (z == 0) ? Xq : ((z == 1) ? Xk : Xv);
  const float* bias = (z == 0) ? bq : ((z == 1) ? bk : bv);
  const unsigned short* Wz = Wt + z * 262144;
  int n0 = blockIdx.x * 64;
  int m0 = blockIdx.y * 64;
  int tid = threadIdx.x;
  int wave = tid >> 6, lane = tid & 63;
  int mrow = lane & 15, quad = lane >> 4;

  f32x4 zero = {0.f, 0.f, 0.f, 0.f};
  f32x4 acc[4];
#pragma unroll
  for (int i = 0; i < 4; ++i) acc[i] = zero;

  const float* ap = X + (m0 + wave * 16 + mrow) * 512 + quad * 8;
  for (int kc = 0; kc < 16; ++kc) {
    float4 a0 = *(const float4*)(ap);
    float4 a1 = *(const float4*)(ap + 4);
    ap += 32;
    bf16x8 af;
    af[0] = (__bf16)a0.x; af[1] = (__bf16)a0.y; af[2] = (__bf16)a0.z; af[3] = (__bf16)a0.w;
    af[4] = (__bf16)a1.x; af[5] = (__bf16)a1.y; af[6] = (__bf16)a1.z; af[7] = (__bf16)a1.w;
    const unsigned short* wp = Wz + (n0 + mrow) * 512 + kc * 32 + quad * 8;
#pragma unroll
    for (int nt = 0; nt < 4; ++nt) {
      bf16x8 bfr = ld_bf8(wp + nt * 8192);  // nt*16 rows * 512
      acc[nt] = mfma16(af, bfr, acc[nt]);
    }
  }

  if (z < 2) {
    unsigned short* dst = (z == 0) ? Qb : Kb;
#pragma unroll
    for (int nt = 0; nt < 4; ++nt) {
      float bv_ = bias[n0 + nt * 16 + mrow];
#pragma unroll
      for (int r = 0; r < 4; ++r) {
        float v = fmaxf(acc[nt][r] + bv_, 0.f);
        dst[(m0 + wave * 16 + quad * 4 + r) * 512 + n0 + nt * 16 + mrow] = f2bf(v);
      }
    }
  } else {
    // stage tile to LDS (row = t-local, col = dh-local), then write transposed
#pragma unroll
    for (int nt = 0; nt < 4; ++nt) {
      float bv_ = bias[n0 + nt * 16 + mrow];
#pragma unroll
      for (int r = 0; r < 4; ++r) {
        float v = fmaxf(acc[nt][r] + bv_, 0.f);
        vlds[(wave * 16 + quad * 4 + r) * 72 + nt * 16 + mrow] = f2bf(v);
      }
    }
    __syncthreads();
    int j = tid >> 2;   // dh-local 0..63
    int tc = tid & 3;   // 16-wide t chunk
    unsigned int w[8];
#pragma unroll
    for (int i = 0; i < 8; ++i) {
      unsigned short lo = vlds[(tc * 16 + 2 * i) * 72 + j];
      unsigned short hi = vlds[(tc * 16 + 2 * i + 1) * 72 + j];
      w[i] = (unsigned)lo | ((unsigned)hi << 16);
    }
    int hh = blockIdx.x;        // head (n-tile == 64 == dh)
    int bb = m0 >> 11;          // batch
    int t0 = m0 & 2047;
    unsigned short* dst = Vt + ((hh * 4 + bb) * 64 + j) * 2048 + t0 + tc * 16;
    *(uint4*)dst = make_uint4(w[0], w[1], w[2], w[3]);
    *(uint4*)(dst + 8) = make_uint4(w[4], w[5], w[6], w[7]);
  }
}

// ---------------------------------------------------------------------------
// Kernel 4: flash attention.  Block = (q-tile of 64, head*batch). 4 waves,
// each wave owns 16 queries x full dh=64, iterates keys in chunks of 64.
// ---------------------------------------------------------------------------
__global__ __launch_bounds__(256) void attn_kernel(
    const unsigned short* __restrict__ Qb, const unsigned short* __restrict__ Kb,
    const unsigned short* __restrict__ Vt, const float* __restrict__ qmask,
    const float* __restrict__ kmask, const float* __restrict__ queries,
    float* __restrict__ out) {
  __shared__ unsigned short plds[4][16 * 72];  // per-wave P C-layout -> A-layout
  int qt = blockIdx.x;
  int hb = blockIdx.y;
  int h = hb >> 2, b = hb & 3;
  int tid = threadIdx.x;
  int wave = tid >> 6, lane = tid & 63;
  int mrow = lane & 15, quad = lane >> 4;
  int q0 = qt * 64;

  // Q A-fragments (held for the whole kernel)
  const unsigned short* qptr =
      Qb + (b * 2048 + q0 + wave * 16 + mrow) * 512 + h * 64 + quad * 8;
  bf16x8 aq0 = ld_bf8(qptr);
  bf16x8 aq1 = ld_bf8(qptr + 32);

  f32x4 zero = {0.f, 0.f, 0.f, 0.f};
  f32x4 oacc[4];
#pragma unroll
  for (int i = 0; i < 4; ++i) oacc[i] = zero;
  float mrun[4], lrun[4];
#pragma unroll
  for (int r = 0; r < 4; ++r) { mrun[r] = -__builtin_inff(); lrun[r] = 0.f; }

  const unsigned short* kbase = Kb + (b * 2048) * 512 + h * 64 + quad * 8;
  const unsigned short* vbase = Vt + hb * 131072 + quad * 8;
  const float* kmb = kmask + b * 2048;
  unsigned short* pw = plds[wave];

  for (int kb = 0; kb < 2048; kb += 64) {
    float s[4][4];
#pragma unroll
    for (int kt = 0; kt < 4; ++kt) {
      const unsigned short* kp = kbase + (kb + kt * 16 + mrow) * 512;
      bf16x8 b0 = ld_bf8(kp);
      bf16x8 b1 = ld_bf8(kp + 32);
      f32x4 sc = zero;
      sc = mfma16(aq0, b0, sc);
      sc = mfma16(aq1, b1, sc);
      float km = kmb[kb + kt * 16 + mrow];  // key col == mrow lane, matches C-layout
#pragma unroll
      for (int r = 0; r < 4; ++r)
        s[kt][r] = (km == 0.f) ? NEG_INF_F : sc[r] * 0.125f;
    }
    // online softmax; row r lives in the 16 lanes of this quad
#pragma unroll
    for (int r = 0; r < 4; ++r) {
      float mx = fmaxf(fmaxf(s[0][r], s[1][r]), fmaxf(s[2][r], s[3][r]));
      mx = fmaxf(mx, __shfl_xor(mx, 1));
      mx = fmaxf(mx, __shfl_xor(mx, 2));
      mx = fmaxf(mx, __shfl_xor(mx, 4));
      mx = fmaxf(mx, __shfl_xor(mx, 8));
      float mnew = fmaxf(mrun[r], mx);
      float alpha = __expf(mrun[r] - mnew);  // exp(-inf)=0 on first iter
      float ssum = 0.f;
#pragma unroll
      for (int kt = 0; kt < 4; ++kt) {
        float p = __expf(s[kt][r] - mnew);
        s[kt][r] = p;
        ssum += p;
      }
      ssum += __shfl_xor(ssum, 1);
      ssum += __shfl_xor(ssum, 2);
      ssum += __shfl_xor(ssum, 4);
      ssum += __shfl_xor(ssum, 8);
      lrun[r] = lrun[r] * alpha + ssum;
      mrun[r] = mnew;
#pragma unroll
      for (int dt = 0; dt < 4; ++dt) oacc[dt][r] *= alpha;
    }
    // P: C-layout -> LDS -> A-layout (wave-private; barrier gives the
    // lgkmcnt(0)+ordering guarantee; all waves run identical trip counts)
#pragma unroll
    for (int kt = 0; kt < 4; ++kt)
#pragma unroll
      for (int r = 0; r < 4; ++r)
        pw[(quad * 4 + r) * 72 + kt * 16 + mrow] = f2bf(s[kt][r]);
    __syncthreads();
    bf16x8 pa0 = ld_bf8(pw + mrow * 72 + quad * 8);
    bf16x8 pa1 = ld_bf8(pw + mrow * 72 + 32 + quad * 8);
#pragma unroll
    for (int dt = 0; dt < 4; ++dt) {
      const unsigned short* vp = vbase + (dt * 16 + mrow) * 2048 + kb;
      bf16x8 v0 = ld_bf8(vp);
      bf16x8 v1 = ld_bf8(vp + 32);
      oacc[dt] = mfma16(pa0, v0, oacc[dt]);
      oacc[dt] = mfma16(pa1, v1, oacc[dt]);
    }
  }

  // epilogue: normalize, query mask, residual, store fp32
#pragma unroll
  for (int r = 0; r < 4; ++r) {
    int qrow = q0 + wave * 16 + quad * 4 + r;
    float qm = qmask[b * 2048 + qrow];
    float inv = qm / lrun[r];
#pragma unroll
    for (int dt = 0; dt < 4; ++dt) {
      int idx = (b * 2048 + qrow) * 512 + h * 64 + dt * 16 + mrow;
      out[idx] = oacc[dt][r] * inv + queries[idx];
    }
  }
}

// ---------------------------------------------------------------------------
// Kernel 5: LayerNorm (unbiased std, eps added to std), in-place on d_out.
// One wave per row of 512.
// ---------------------------------------------------------------------------
__global__ __launch_bounds__(256) void ln_kernel(float* __restrict__ out,
                                                 const float* __restrict__ gamma,
                                                 const float* __restrict__ beta) {
  int row = blockIdx.x * 4 + (threadIdx.x >> 6);
  int lane = threadIdx.x & 63;
  float* p = out + row * 512;
  float4 v1 = ((const float4*)p)[lane];
  float4 v2 = ((const float4*)p)[64 + lane];
  float s = v1.x + v1.y + v1.z + v1.w + v2.x + v2.y + v2.z + v2.w;
  float sq = v1.x * v1.x + v1.y * v1.y + v1.z * v1.z + v1.w * v1.w +
             v2.x * v2.x + v2.y * v2.y + v2.z * v2.z + v2.w * v2.w;
#pragma unroll
  for (int off = 32; off > 0; off >>= 1) {
    s += __shfl_xor(s, off);
    sq += __shfl_xor(sq, off);
  }
  float mean = s * (1.f / 512.f);
  float var = fmaxf((sq - 512.f * mean * mean) * (1.f / 511.f), 0.f);
  float inv = 1.f / (sqrtf(var) + 1e-8f);
  float4 g1 = ((const float4*)gamma)[lane];
  float4 g2 = ((const float4*)gamma)[64 + lane];
  float4 b1 = ((const float4*)beta)[lane];
  float4 b2 = ((const float4*)beta)[64 + lane];
  v1.x = g1.x * (v1.x - mean) * inv + b1.x;
  v1.y = g1.y * (v1.y - mean) * inv + b1.y;
  v1.z = g1.z * (v1.z - mean) * inv + b1.z;
  v1.w = g1.w * (v1.w - mean) * inv + b1.w;
  v2.x = g2.x * (v2.x - mean) * inv + b2.x;
  v2.y = g2.y * (v2.y - mean) * inv + b2.y;
  v2.z = g2.z * (v2.z - mean) * inv + b2.z;
  v2.w = g2.w * (v2.w - mean) * inv + b2.w;
  ((float4*)p)[lane] = v1;
  ((float4*)p)[64 + lane] = v2;
}

// ---------------------------------------------------------------------------
extern "C" void kernel_launch(void* const* d_in, const int* in_sizes, int n_in,
                              void* d_out, int out_size, void* d_ws, size_t ws_size,
                              hipStream_t stream) {
  (void)in_sizes; (void)n_in; (void)out_size; (void)ws_size;
  const float* queries = (const float*)d_in[0];
  const float* keys    = (const float*)d_in[1];
  const float* values  = (const float*)d_in[2];
  const float* Wq = (const float*)d_in[3];
  const float* bq = (const float*)d_in[4];
  const float* Wk = (const float*)d_in[5];
  const float* bk = (const float*)d_in[6];
  const float* Wv = (const float*)d_in[7];
  const float* bv = (const float*)d_in[8];
  const float* gamma = (const float*)d_in[9];
  const float* beta  = (const float*)d_in[10];
  float* out = (float*)d_out;

  char* ws = (char*)d_ws;
  unsigned short* Qb = (unsigned short*)(ws);                    // 8 MB
  unsigned short* Kb = (unsigned short*)(ws + 8 * 1024 * 1024);  // 8 MB
  unsigned short* Vt = (unsigned short*)(ws + 16 * 1024 * 1024); // 8 MB  [32][64][2048]
  unsigned short* Wt = (unsigned short*)(ws + 24 * 1024 * 1024); // 1.5 MB
  float* qmask = (float*)(ws + 24 * 1024 * 1024 + 3 * 512 * 512 * 2);
  float* kmask = qmask + 8192;

  wt_kernel<<<384, 256, 0, stream>>>(Wq, Wk, Wv, Wt);
  mask_kernel<<<4096, 256, 0, stream>>>(queries, keys, qmask, kmask);
  proj_kernel<<<dim3(8, 128, 3), 256, 0, stream>>>(queries, keys, values, bq, bk, bv,
                                                   Wt, Qb, Kb, Vt);
  attn_kernel<<<dim3(32, 32), 256, 0, stream>>>(Qb, Kb, Vt, qmask, kmask, queries, out);
  ln_kernel<<<2048, 256, 0, stream>>>(out, gamma, beta);
}

// Round 2
// 321.816 us; speedup vs baseline: 1.5102x; 1.5102x over previous
//
#include <hip/hip_runtime.h>

// R2: attention rewritten key-split per wave (wave-private K/V direct from
// global, no main-loop barriers), max-free exp2 softmax (scores >= 0 since
// Q,K are ReLU outputs; overflow impossible), 0.125*log2e folded into Qb.
// proj grid swapped to m-major for XCD-local A reuse.

typedef __attribute__((ext_vector_type(8))) __bf16 bf16x8;
typedef __attribute__((ext_vector_type(4))) float f32x4;

#if __has_builtin(__builtin_amdgcn_exp2f)
#define EXP2F __builtin_amdgcn_exp2f
#else
#define EXP2F exp2f
#endif

#define QSCALE (0.125f * 1.4426950408889634f)  // fold /sqrt(64) and ln->log2

__device__ __forceinline__ unsigned short f2bf(float f) {
  return __builtin_bit_cast(unsigned short, (__bf16)f);
}
__device__ __forceinline__ unsigned pk2(float a, float b) {
  return (unsigned)f2bf(a) | ((unsigned)f2bf(b) << 16);
}
__device__ __forceinline__ f32x4 mfma16(bf16x8 a, bf16x8 b, f32x4 c) {
  return __builtin_amdgcn_mfma_f32_16x16x32_bf16(a, b, c, 0, 0, 0);
}
__device__ __forceinline__ bf16x8 ld_bf8(const unsigned short* p) {
  return *(const bf16x8*)p;
}

// ---------------------------------------------------------------------------
// Kernel 1: transpose + convert the three 512x512 weight matrices to bf16,
// layout Wt[z][n][k] (n-major) so MFMA B-fragments read contiguous k.
// ---------------------------------------------------------------------------
__global__ __launch_bounds__(256) void wt_kernel(const float* __restrict__ Wq,
                                                 const float* __restrict__ Wk,
                                                 const float* __restrict__ Wv,
                                                 unsigned short* __restrict__ Wt) {
  int idx = blockIdx.x * 256 + threadIdx.x;
  int o = idx * 8;                  // output element index, 3*512*512 total
  int z = o >> 18;                  // 512*512 = 262144
  int rem = o & 262143;
  int n = rem >> 9;
  int k0 = rem & 511;
  const float* W = (z == 0) ? Wq : ((z == 1) ? Wk : Wv);
  unsigned int w[4];
#pragma unroll
  for (int i = 0; i < 4; ++i) {
    unsigned short lo = f2bf(W[(k0 + 2 * i) * 512 + n]);
    unsigned short hi = f2bf(W[(k0 + 2 * i + 1) * 512 + n]);
    w[i] = (unsigned)lo | ((unsigned)hi << 16);
  }
  *(uint4*)(Wt + o) = make_uint4(w[0], w[1], w[2], w[3]);
}

// ---------------------------------------------------------------------------
// Kernel 2: key/query padding masks: sign(|row sum|) of the RAW inputs.
// ---------------------------------------------------------------------------
__global__ __launch_bounds__(256) void mask_kernel(const float* __restrict__ q,
                                                   const float* __restrict__ k,
                                                   float* __restrict__ qmask,
                                                   float* __restrict__ kmask) {
  int w = blockIdx.x * 4 + (threadIdx.x >> 6);
  int lane = threadIdx.x & 63;
  const float* src = (w < 8192) ? q : k;
  int row = w & 8191;
  const float4* p = (const float4*)(src + row * 512);
  float4 v1 = p[lane];
  float4 v2 = p[64 + lane];
  float s = v1.x + v1.y + v1.z + v1.w + v2.x + v2.y + v2.z + v2.w;
#pragma unroll
  for (int off = 32; off > 0; off >>= 1) s += __shfl_xor(s, off);
  if (lane == 0) {
    float m = (s == 0.0f) ? 0.0f : 1.0f;
    if (w < 8192) qmask[row] = m; else kmask[row] = m;
  }
}

// ---------------------------------------------------------------------------
// Kernel 3: QKV projection.  C[8192,512] = relu(X @ W + b) in bf16.
// Grid (m=128, n=8, z=3): m fastest -> all n-blocks of one A row-block land
// on the same XCD (id%8 == m%8) so A is fetched once per XCD.
// z==0 (Q) is additionally scaled by QSCALE (exp2-domain softmax).
// z==2 (V) is written transposed per head: Vt[(h*4+b)*64 + j][t]  (bf16).
// ---------------------------------------------------------------------------
__global__ __launch_bounds__(256) void proj_kernel(
    const float* __restrict__ Xq, const float* __restrict__ Xk,
    const float* __restrict__ Xv, const float* __restrict__ bq,
    const float* __restrict__ bk, const float* __restrict__ bv,
    const unsigned short* __restrict__ Wt, unsigned short* __restrict__ Qb,
    unsigned short* __restrict__ Kb, unsigned short* __restrict__ Vt) {
  __shared__ unsigned short vlds[64 * 72];
  int z = blockIdx.z;
  const float* X = (z == 0) ? Xq : ((z == 1) ? Xk : Xv);
  const float* bias = (z == 0) ? bq : ((z == 1) ? bk : bv);
  const unsigned short* Wz = Wt + z * 262144;
  int m0 = blockIdx.x * 64;
  int n0 = blockIdx.y * 64;
  int tid = threadIdx.x;
  int wave = tid >> 6, lane = tid & 63;
  int mrow = lane & 15, quad = lane >> 4;

  f32x4 zero = {0.f, 0.f, 0.f, 0.f};
  f32x4 acc[4];
#pragma unroll
  for (int i = 0; i < 4; ++i) acc[i] = zero;

  const float* ap = X + (m0 + wave * 16 + mrow) * 512 + quad * 8;
  for (int kc = 0; kc < 16; ++kc) {
    float4 a0 = *(const float4*)(ap);
    float4 a1 = *(const float4*)(ap + 4);
    ap += 32;
    bf16x8 af;
    af[0] = (__bf16)a0.x; af[1] = (__bf16)a0.y; af[2] = (__bf16)a0.z; af[3] = (__bf16)a0.w;
    af[4] = (__bf16)a1.x; af[5] = (__bf16)a1.y; af[6] = (__bf16)a1.z; af[7] = (__bf16)a1.w;
    const unsigned short* wp = Wz + (n0 + mrow) * 512 + kc * 32 + quad * 8;
#pragma unroll
    for (int nt = 0; nt < 4; ++nt) {
      bf16x8 bfr = ld_bf8(wp + nt * 8192);
      acc[nt] = mfma16(af, bfr, acc[nt]);
    }
  }

  if (z < 2) {
    unsigned short* dst = (z == 0) ? Qb : Kb;
    float sc = (z == 0) ? QSCALE : 1.0f;
#pragma unroll
    for (int nt = 0; nt < 4; ++nt) {
      float bv_ = bias[n0 + nt * 16 + mrow];
#pragma unroll
      for (int r = 0; r < 4; ++r) {
        float v = fmaxf(acc[nt][r] + bv_, 0.f) * sc;
        dst[(m0 + wave * 16 + quad * 4 + r) * 512 + n0 + nt * 16 + mrow] = f2bf(v);
      }
    }
  } else {
#pragma unroll
    for (int nt = 0; nt < 4; ++nt) {
      float bv_ = bias[n0 + nt * 16 + mrow];
#pragma unroll
      for (int r = 0; r < 4; ++r) {
        float v = fmaxf(acc[nt][r] + bv_, 0.f);
        vlds[(wave * 16 + quad * 4 + r) * 72 + nt * 16 + mrow] = f2bf(v);
      }
    }
    __syncthreads();
    int j = tid >> 2;   // dh-local 0..63
    int tc = tid & 3;   // 16-wide t chunk
    unsigned int w[8];
#pragma unroll
    for (int i = 0; i < 8; ++i) {
      unsigned short lo = vlds[(tc * 16 + 2 * i) * 72 + j];
      unsigned short hi = vlds[(tc * 16 + 2 * i + 1) * 72 + j];
      w[i] = (unsigned)lo | ((unsigned)hi << 16);
    }
    int hh = blockIdx.y;        // head (n-tile == 64 == dh)
    int bb = m0 >> 11;          // batch
    int t0 = m0 & 2047;
    unsigned short* dst = Vt + ((hh * 4 + bb) * 64 + j) * 2048 + t0 + tc * 16;
    *(uint4*)dst = make_uint4(w[0], w[1], w[2], w[3]);
    *(uint4*)(dst + 8) = make_uint4(w[4], w[5], w[6], w[7]);
  }
}

// ---------------------------------------------------------------------------
// Kernel 4: attention, key-split across waves.
// Block = (hb, q-tile of 64). Wave w owns keys {chunk + w*32 .. +31} of each
// 128-key chunk and ALL 64 queries -> K/V fragments are wave-private, loaded
// straight from global (L2); only P makes an LDS round-trip (wave-private,
// no barriers in the main loop). Scores are >= 0 (ReLU inputs) so softmax is
// max-free in exp2 domain; l is reduced in the epilogue. Partial O summed
// across waves through LDS (aliased onto the P region).
// Layouts (m89-verified): A[m=lane&15][k=quad*8+j]; C/D col=lane&15 (n),
// row=quad*4+reg (m). QK^T computed as S^T=K*Q^T; PV as O^T=V^T*P^T.
// ---------------------------------------------------------------------------
__global__ __launch_bounds__(256) void attn_kernel(
    const unsigned short* __restrict__ Qb, const unsigned short* __restrict__ Kb,
    const unsigned short* __restrict__ Vt, const float* __restrict__ qmask,
    const float* __restrict__ kmask, const float* __restrict__ queries,
    float* __restrict__ out) {
  __shared__ unsigned short plds[4][64 * 40];  // per-wave P [64 q][32 k + pad]
  __shared__ float lbuf[4][64];
  float* Obuf = (float*)&plds[0][0];           // epilogue alias: [64 q][68]

  int hb = blockIdx.x;                         // h*4+b ; hb%8 -> XCD locality
  int qt = blockIdx.y;
  int h = hb >> 2, b = hb & 3;
  int q0 = qt * 64;
  int tid = threadIdx.x;
  int w = tid >> 6, lane = tid & 63;
  int mrow = lane & 15, quad = lane >> 4;
  unsigned short* pw = &plds[w][0];

  // Q fragments: B[n=query qn*16+mrow][k=dh kh*32+quad*8] — same in all waves
  bf16x8 qf[4][2];
  {
    const unsigned short* qp = Qb + (b * 2048 + q0 + mrow) * 512 + h * 64 + quad * 8;
#pragma unroll
    for (int qn = 0; qn < 4; ++qn) {
      qf[qn][0] = ld_bf8(qp + qn * 8192);
      qf[qn][1] = ld_bf8(qp + qn * 8192 + 32);
    }
  }

  f32x4 zero = {0.f, 0.f, 0.f, 0.f};
  f32x4 oacc[4][4];
#pragma unroll
  for (int i = 0; i < 4; ++i)
#pragma unroll
    for (int j = 0; j < 4; ++j) oacc[i][j] = zero;
  float lpart[4] = {0.f, 0.f, 0.f, 0.f};

  const int kidx = (b * 2048 + w * 32 + mrow) * 512 + h * 64 + quad * 8;
  const int vidx = (hb * 64 + mrow) * 2048 + w * 32 + quad * 8;
  const int kmi = b * 2048 + w * 32 + quad * 4;
  const int pbase = mrow * 40 + quad * 4;      // P write base (shorts), +qn*640
  const int prd = mrow * 40 + quad * 8;        // P read base, +qn*640

  // K fragments A[m=key mt*16+mrow][k=dh kh*32+quad*8], prefetched 1 iter ahead
  bf16x8 kf[2][2];
#pragma unroll
  for (int mt = 0; mt < 2; ++mt) {
    kf[mt][0] = ld_bf8(Kb + kidx + mt * 8192);
    kf[mt][1] = ld_bf8(Kb + kidx + mt * 8192 + 32);
  }

  for (int it = 0; it < 16; ++it) {
    int kb = it << 7;
    // --- QK^T: S^T tiles [32 keys x 64 queries]
    f32x4 sacc[2][4];
#pragma unroll
    for (int mt = 0; mt < 2; ++mt)
#pragma unroll
      for (int qn = 0; qn < 4; ++qn) {
        f32x4 s = mfma16(kf[mt][0], qf[qn][0], zero);
        sacc[mt][qn] = mfma16(kf[mt][1], qf[qn][1], s);
      }
    // --- V fragments (A[m=dh dt*16+mrow][k=key quad*8+j]) + key mask
    bf16x8 vf[4];
#pragma unroll
    for (int dt = 0; dt < 4; ++dt) vf[dt] = ld_bf8(Vt + vidx + dt * 32768 + kb);
    f32x4 km[2];
    km[0] = *(const f32x4*)(kmask + kmi + kb);
    km[1] = *(const f32x4*)(kmask + kmi + kb + 16);
    // --- max-free softmax: p = exp2(s)*km ; accumulate l ; pack to LDS
#pragma unroll
    for (int mt = 0; mt < 2; ++mt)
#pragma unroll
      for (int qn = 0; qn < 4; ++qn) {
        f32x4 p;
#pragma unroll
        for (int r = 0; r < 4; ++r) p[r] = EXP2F(sacc[mt][qn][r]) * km[mt][r];
        lpart[qn] += p[0] + p[1] + p[2] + p[3];
        *(uint2*)(pw + qn * 640 + pbase + mt * 16) =
            make_uint2(pk2(p[0], p[1]), pk2(p[2], p[3]));
      }
    // --- P back as B-operand [n=query][k=key quad*8+j]
    bf16x8 pf[4];
#pragma unroll
    for (int qn = 0; qn < 4; ++qn) pf[qn] = ld_bf8(pw + qn * 640 + prd);
    // --- prefetch next K chunk (wraps on last iter; result unused)
    int nkb = ((it + 1) & 15) << 7;
    bf16x8 nkf[2][2];
#pragma unroll
    for (int mt = 0; mt < 2; ++mt) {
      nkf[mt][0] = ld_bf8(Kb + kidx + nkb * 512 + mt * 8192);
      nkf[mt][1] = ld_bf8(Kb + kidx + nkb * 512 + mt * 8192 + 32);
    }
    // --- PV: O^T += V^T * P^T
#pragma unroll
    for (int dt = 0; dt < 4; ++dt)
#pragma unroll
      for (int qn = 0; qn < 4; ++qn)
        oacc[dt][qn] = mfma16(vf[dt], pf[qn], oacc[dt][qn]);
#pragma unroll
    for (int mt = 0; mt < 2; ++mt) {
      kf[mt][0] = nkf[mt][0];
      kf[mt][1] = nkf[mt][1];
    }
  }

  // --- epilogue: reduce l across quads, publish per-wave l
#pragma unroll
  for (int qn = 0; qn < 4; ++qn) {
    lpart[qn] += __shfl_xor(lpart[qn], 16);
    lpart[qn] += __shfl_xor(lpart[qn], 32);
  }
  if (quad == 0) {
#pragma unroll
    for (int qn = 0; qn < 4; ++qn) lbuf[w][qn * 16 + mrow] = lpart[qn];
  }
  __syncthreads();  // all waves done with plds; lbuf visible

  // --- sum partial O across waves into Obuf [64][68] (aliases plds)
  for (int ph = 0; ph < 4; ++ph) {
    if (w == ph) {
#pragma unroll
      for (int dt = 0; dt < 4; ++dt)
#pragma unroll
        for (int qn = 0; qn < 4; ++qn) {
          float* dst = Obuf + (qn * 16 + mrow) * 68 + dt * 16 + quad * 4;
          f32x4 v = oacc[dt][qn];
          if (ph) {
            v[0] += dst[0]; v[1] += dst[1]; v[2] += dst[2]; v[3] += dst[3];
          }
          dst[0] = v[0]; dst[1] = v[1]; dst[2] = v[2]; dst[3] = v[3];
        }
    }
    __syncthreads();
  }

  // --- scale by qmask/l, add residual, store fp32 (coalesced float4)
#pragma unroll
  for (int i = 0; i < 4; ++i) {
    int qr = w * 16 + i * 4 + quad;
    float l = lbuf[0][qr] + lbuf[1][qr] + lbuf[2][qr] + lbuf[3][qr];
    int qg = b * 2048 + q0 + qr;
    float inv = qmask[qg] / l;
    const float* ob = Obuf + qr * 68 + mrow * 4;
    const float4 res = *(const float4*)(queries + qg * 512 + h * 64 + mrow * 4);
    float4 r;
    r.x = ob[0] * inv + res.x;
    r.y = ob[1] * inv + res.y;
    r.z = ob[2] * inv + res.z;
    r.w = ob[3] * inv + res.w;
    *(float4*)(out + qg * 512 + h * 64 + mrow * 4) = r;
  }
}

// ---------------------------------------------------------------------------
// Kernel 5: LayerNorm (unbiased std, eps added to std), in-place on d_out.
// ---------------------------------------------------------------------------
__global__ __launch_bounds__(256) void ln_kernel(float* __restrict__ out,
                                                 const float* __restrict__ gamma,
                                                 const float* __restrict__ beta) {
  int row = blockIdx.x * 4 + (threadIdx.x >> 6);
  int lane = threadIdx.x & 63;
  float* p = out + row * 512;
  float4 v1 = ((const float4*)p)[lane];
  float4 v2 = ((const float4*)p)[64 + lane];
  float s = v1.x + v1.y + v1.z + v1.w + v2.x + v2.y + v2.z + v2.w;
  float sq = v1.x * v1.x + v1.y * v1.y + v1.z * v1.z + v1.w * v1.w +
             v2.x * v2.x + v2.y * v2.y + v2.z * v2.z + v2.w * v2.w;
#pragma unroll
  for (int off = 32; off > 0; off >>= 1) {
    s += __shfl_xor(s, off);
    sq += __shfl_xor(sq, off);
  }
  float mean = s * (1.f / 512.f);
  float var = fmaxf((sq - 512.f * mean * mean) * (1.f / 511.f), 0.f);
  float inv = 1.f / (sqrtf(var) + 1e-8f);
  float4 g1 = ((const float4*)gamma)[lane];
  float4 g2 = ((const float4*)gamma)[64 + lane];
  float4 b1 = ((const float4*)beta)[lane];
  float4 b2 = ((const float4*)beta)[64 + lane];
  v1.x = g1.x * (v1.x - mean) * inv + b1.x;
  v1.y = g1.y * (v1.y - mean) * inv + b1.y;
  v1.z = g1.z * (v1.z - mean) * inv + b1.z;
  v1.w = g1.w * (v1.w - mean) * inv + b1.w;
  v2.x = g2.x * (v2.x - mean) * inv + b2.x;
  v2.y = g2.y * (v2.y - mean) * inv + b2.y;
  v2.z = g2.z * (v2.z - mean) * inv + b2.z;
  v2.w = g2.w * (v2.w - mean) * inv + b2.w;
  ((float4*)p)[lane] = v1;
  ((float4*)p)[64 + lane] = v2;
}

// ---------------------------------------------------------------------------
extern "C" void kernel_launch(void* const* d_in, const int* in_sizes, int n_in,
                              void* d_out, int out_size, void* d_ws, size_t ws_size,
                              hipStream_t stream) {
  (void)in_sizes; (void)n_in; (void)out_size; (void)ws_size;
  const float* queries = (const float*)d_in[0];
  const float* keys    = (const float*)d_in[1];
  const float* values  = (const float*)d_in[2];
  const float* Wq = (const float*)d_in[3];
  const float* bq = (const float*)d_in[4];
  const float* Wk = (const float*)d_in[5];
  const float* bk = (const float*)d_in[6];
  const float* Wv = (const float*)d_in[7];
  const float* bv = (const float*)d_in[8];
  const float* gamma = (const float*)d_in[9];
  const float* beta  = (const float*)d_in[10];
  float* out = (float*)d_out;

  char* ws = (char*)d_ws;
  unsigned short* Qb = (unsigned short*)(ws);                    // 8 MB
  unsigned short* Kb = (unsigned short*)(ws + 8 * 1024 * 1024);  // 8 MB
  unsigned short* Vt = (unsigned short*)(ws + 16 * 1024 * 1024); // 8 MB  [32][64][2048]
  unsigned short* Wt = (unsigned short*)(ws + 24 * 1024 * 1024); // 1.5 MB
  float* qmask = (float*)(ws + 24 * 1024 * 1024 + 3 * 512 * 512 * 2);
  float* kmask = qmask + 8192;

  wt_kernel<<<384, 256, 0, stream>>>(Wq, Wk, Wv, Wt);
  mask_kernel<<<4096, 256, 0, stream>>>(queries, keys, qmask, kmask);
  proj_kernel<<<dim3(128, 8, 3), 256, 0, stream>>>(queries, keys, values, bq, bk, bv,
                                                   Wt, Qb, Kb, Vt);
  attn_kernel<<<dim3(32, 32), 256, 0, stream>>>(Qb, Kb, Vt, qmask, kmask, queries, out);
  ln_kernel<<<2048, 256, 0, stream>>>(out, gamma, beta);
}

// Round 3
// 215.720 us; speedup vs baseline: 2.2529x; 1.4918x over previous
//
#include <hip/hip_runtime.h>

// R3: proj rewritten as m97-style LDS-staged MFMA GEMM (128x128 tile, BK=32,
// global_load_lds width-16 async staging, two-barrier K-loop). A stays fp32
// in global and is converted to bf16 after the LDS read. V is stored directly
// transposed from the accumulators. attn/ln/mask/wt unchanged from R2.

typedef __attribute__((ext_vector_type(8))) __bf16 bf16x8;
typedef __attribute__((ext_vector_type(4))) float f32x4;

#if __has_builtin(__builtin_amdgcn_exp2f)
#define EXP2F __builtin_amdgcn_exp2f
#else
#define EXP2F exp2f
#endif

#define QSCALE (0.125f * 1.4426950408889634f)  // fold /sqrt(64) and ln->log2

__device__ __forceinline__ unsigned short f2bf(float f) {
  return __builtin_bit_cast(unsigned short, (__bf16)f);
}
__device__ __forceinline__ unsigned pk2(float a, float b) {
  return (unsigned)f2bf(a) | ((unsigned)f2bf(b) << 16);
}
__device__ __forceinline__ f32x4 mfma16(bf16x8 a, bf16x8 b, f32x4 c) {
  return __builtin_amdgcn_mfma_f32_16x16x32_bf16(a, b, c, 0, 0, 0);
}
__device__ __forceinline__ bf16x8 ld_bf8(const unsigned short* p) {
  return *(const bf16x8*)p;
}
// async global->LDS, 16 B per lane; LDS dst must be wave-uniform base + lane*16
__device__ __forceinline__ void g2l16(const void* g, void* l) {
  __builtin_amdgcn_global_load_lds(
      (const __attribute__((address_space(1))) void*)g,
      (__attribute__((address_space(3))) void*)l, 16, 0, 0);
}

// ---------------------------------------------------------------------------
// Kernel 1: transpose + convert the three 512x512 weight matrices to bf16,
// layout Wt[z][n][k] (n-major) so MFMA B-fragments read contiguous k.
// ---------------------------------------------------------------------------
__global__ __launch_bounds__(256) void wt_kernel(const float* __restrict__ Wq,
                                                 const float* __restrict__ Wk,
                                                 const float* __restrict__ Wv,
                                                 unsigned short* __restrict__ Wt) {
  int idx = blockIdx.x * 256 + threadIdx.x;
  int o = idx * 8;
  int z = o >> 18;
  int rem = o & 262143;
  int n = rem >> 9;
  int k0 = rem & 511;
  const float* W = (z == 0) ? Wq : ((z == 1) ? Wk : Wv);
  unsigned int w[4];
#pragma unroll
  for (int i = 0; i < 4; ++i) {
    unsigned short lo = f2bf(W[(k0 + 2 * i) * 512 + n]);
    unsigned short hi = f2bf(W[(k0 + 2 * i + 1) * 512 + n]);
    w[i] = (unsigned)lo | ((unsigned)hi << 16);
  }
  *(uint4*)(Wt + o) = make_uint4(w[0], w[1], w[2], w[3]);
}

// ---------------------------------------------------------------------------
// Kernel 2: key/query padding masks: sign(|row sum|) of the RAW inputs.
// ---------------------------------------------------------------------------
__global__ __launch_bounds__(256) void mask_kernel(const float* __restrict__ q,
                                                   const float* __restrict__ k,
                                                   float* __restrict__ qmask,
                                                   float* __restrict__ kmask) {
  int w = blockIdx.x * 4 + (threadIdx.x >> 6);
  int lane = threadIdx.x & 63;
  const float* src = (w < 8192) ? q : k;
  int row = w & 8191;
  const float4* p = (const float4*)(src + row * 512);
  float4 v1 = p[lane];
  float4 v2 = p[64 + lane];
  float s = v1.x + v1.y + v1.z + v1.w + v2.x + v2.y + v2.z + v2.w;
#pragma unroll
  for (int off = 32; off > 0; off >>= 1) s += __shfl_xor(s, off);
  if (lane == 0) {
    float m = (s == 0.0f) ? 0.0f : 1.0f;
    if (w < 8192) qmask[row] = m; else kmask[row] = m;
  }
}

// ---------------------------------------------------------------------------
// Kernel 3: QKV projection as m97-style GEMM.
// Grid (192 m-blocks, 4 n-blocks); m-block 0..63 -> z=0 (Q), 64..127 -> z=1
// (K), 128..191 -> z=2 (V). Tile 128x128, BK=32, 4 waves (2x2 of 64x64).
// A (fp32 activations) staged via global_load_lds into two [128][16] fp32
// half-K buffers (64-B rows, m97 bank pattern); B (bf16 Wt) staged [128][32].
// Epilogue: bias+relu (+QSCALE for Q); V written transposed to Vt.
// ---------------------------------------------------------------------------
__global__ __launch_bounds__(256, 3) void proj_kernel(
    const float* __restrict__ Xq, const float* __restrict__ Xk,
    const float* __restrict__ Xv, const float* __restrict__ bq,
    const float* __restrict__ bk, const float* __restrict__ bv,
    const unsigned short* __restrict__ Wt, unsigned short* __restrict__ Qb,
    unsigned short* __restrict__ Kb, unsigned short* __restrict__ Vt) {
  __shared__ float Asm[2][128][16];        // [k-half][row][16 fp32] = 2 x 8 KB
  __shared__ unsigned short Bsm[128][32];  // [row][32 k bf16] = 8 KB

  int tid = threadIdx.x;
  int m0g = blockIdx.x * 128;
  int z = m0g >> 13;
  int m0 = m0g & 8191;
  int n0 = blockIdx.y * 128;
  const float* X = (z == 0) ? Xq : ((z == 1) ? Xk : Xv);
  const float* bias = (z == 0) ? bq : ((z == 1) ? bk : bv);
  const unsigned short* Wz = Wt + z * 262144;

  int w = tid >> 6, lane = tid & 63;
  int wm = w >> 1, wn = w & 1;
  int mrow = lane & 15, quad = lane >> 4;

  // staging: lane -> (row = tid/4, 16-B chunk = tid%4); 2 row-groups of 64
  int srow = tid >> 2, schk = tid & 3;
  const float* gA = X + (m0 + srow) * 512 + schk * 4;
  const unsigned short* gB = Wz + (n0 + srow) * 512 + schk * 8;
  char* lA = (char*)&Asm[0][0][0] + tid * 16;
  char* lB = (char*)&Bsm[0][0] + tid * 16;

  // frag-read bases: lane's k = quad*8..+7 -> half = quad>>1, chunk = (quad&1)*8
  const float* rA = &Asm[quad >> 1][0][(quad & 1) * 8];
  const unsigned short* rB = &Bsm[0][quad * 8];

  f32x4 zero = {0.f, 0.f, 0.f, 0.f};
  f32x4 acc[4][4];
#pragma unroll
  for (int i = 0; i < 4; ++i)
#pragma unroll
    for (int j = 0; j < 4; ++j) acc[i][j] = zero;

  for (int kc = 0; kc < 16; ++kc) {
    int ko = kc * 32;
    // A: 4 issues (2 k-halves x 2 row-groups), B: 2 issues
    g2l16(gA + ko, lA);
    g2l16(gA + ko + 64 * 512, lA + 4096);
    g2l16(gA + ko + 16, lA + 8192);
    g2l16(gA + ko + 16 + 64 * 512, lA + 12288);
    g2l16(gB + ko, lB);
    g2l16(gB + ko + 64 * 512, lB + 4096);
    __syncthreads();

    bf16x8 af[4], bfr[4];
#pragma unroll
    for (int mt = 0; mt < 4; ++mt) {
      const float* pa = rA + (wm * 64 + mt * 16 + mrow) * 16;
      f32x4 lo = *(const f32x4*)pa;
      f32x4 hi = *(const f32x4*)(pa + 4);
      bf16x8 t;
      t[0] = (__bf16)lo[0]; t[1] = (__bf16)lo[1];
      t[2] = (__bf16)lo[2]; t[3] = (__bf16)lo[3];
      t[4] = (__bf16)hi[0]; t[5] = (__bf16)hi[1];
      t[6] = (__bf16)hi[2]; t[7] = (__bf16)hi[3];
      af[mt] = t;
    }
#pragma unroll
    for (int nt = 0; nt < 4; ++nt)
      bfr[nt] = ld_bf8(rB + (wn * 64 + nt * 16 + mrow) * 32);
#pragma unroll
    for (int mt = 0; mt < 4; ++mt)
#pragma unroll
      for (int nt = 0; nt < 4; ++nt)
        acc[mt][nt] = mfma16(af[mt], bfr[nt], acc[mt][nt]);
    __syncthreads();
  }

  // epilogue: C[m = m0+wm*64+mt*16+quad*4+r][n = n0+wn*64+nt*16+mrow]
  if (z < 2) {
    unsigned short* dst = (z == 0) ? Qb : Kb;
    float sc = (z == 0) ? QSCALE : 1.0f;
#pragma unroll
    for (int nt = 0; nt < 4; ++nt) {
      int n = n0 + wn * 64 + nt * 16 + mrow;
      float bv_ = bias[n];
#pragma unroll
      for (int mt = 0; mt < 4; ++mt) {
        int m = m0 + wm * 64 + mt * 16 + quad * 4;
#pragma unroll
        for (int r = 0; r < 4; ++r) {
          float v = fmaxf(acc[mt][nt][r] + bv_, 0.f) * sc;
          dst[(m + r) * 512 + n] = f2bf(v);
        }
      }
    }
  } else {
    // V: store transposed Vt[(h*4+b)*64 + j][t], 4 t's packed per 8-B store
#pragma unroll
    for (int nt = 0; nt < 4; ++nt) {
      int n = n0 + wn * 64 + nt * 16 + mrow;
      int hh = n >> 6, jj = n & 63;
      float bv_ = bias[n];
#pragma unroll
      for (int mt = 0; mt < 4; ++mt) {
        int grow = m0 + wm * 64 + mt * 16 + quad * 4;
        int bb = grow >> 11, tl = grow & 2047;
        float p0 = fmaxf(acc[mt][nt][0] + bv_, 0.f);
        float p1 = fmaxf(acc[mt][nt][1] + bv_, 0.f);
        float p2 = fmaxf(acc[mt][nt][2] + bv_, 0.f);
        float p3 = fmaxf(acc[mt][nt][3] + bv_, 0.f);
        *(uint2*)(Vt + ((hh * 4 + bb) * 64 + jj) * 2048 + tl) =
            make_uint2(pk2(p0, p1), pk2(p2, p3));
      }
    }
  }
}

// ---------------------------------------------------------------------------
// Kernel 4: attention, key-split across waves (unchanged from R2).
// ---------------------------------------------------------------------------
__global__ __launch_bounds__(256) void attn_kernel(
    const unsigned short* __restrict__ Qb, const unsigned short* __restrict__ Kb,
    const unsigned short* __restrict__ Vt, const float* __restrict__ qmask,
    const float* __restrict__ kmask, const float* __restrict__ queries,
    float* __restrict__ out) {
  __shared__ unsigned short plds[4][64 * 40];
  __shared__ float lbuf[4][64];
  float* Obuf = (float*)&plds[0][0];

  int hb = blockIdx.x;
  int qt = blockIdx.y;
  int h = hb >> 2, b = hb & 3;
  int q0 = qt * 64;
  int tid = threadIdx.x;
  int w = tid >> 6, lane = tid & 63;
  int mrow = lane & 15, quad = lane >> 4;
  unsigned short* pw = &plds[w][0];

  bf16x8 qf[4][2];
  {
    const unsigned short* qp = Qb + (b * 2048 + q0 + mrow) * 512 + h * 64 + quad * 8;
#pragma unroll
    for (int qn = 0; qn < 4; ++qn) {
      qf[qn][0] = ld_bf8(qp + qn * 8192);
      qf[qn][1] = ld_bf8(qp + qn * 8192 + 32);
    }
  }

  f32x4 zero = {0.f, 0.f, 0.f, 0.f};
  f32x4 oacc[4][4];
#pragma unroll
  for (int i = 0; i < 4; ++i)
#pragma unroll
    for (int j = 0; j < 4; ++j) oacc[i][j] = zero;
  float lpart[4] = {0.f, 0.f, 0.f, 0.f};

  const int kidx = (b * 2048 + w * 32 + mrow) * 512 + h * 64 + quad * 8;
  const int vidx = (hb * 64 + mrow) * 2048 + w * 32 + quad * 8;
  const int kmi = b * 2048 + w * 32 + quad * 4;
  const int pbase = mrow * 40 + quad * 4;
  const int prd = mrow * 40 + quad * 8;

  bf16x8 kf[2][2];
#pragma unroll
  for (int mt = 0; mt < 2; ++mt) {
    kf[mt][0] = ld_bf8(Kb + kidx + mt * 8192);
    kf[mt][1] = ld_bf8(Kb + kidx + mt * 8192 + 32);
  }

  for (int it = 0; it < 16; ++it) {
    int kb = it << 7;
    f32x4 sacc[2][4];
#pragma unroll
    for (int mt = 0; mt < 2; ++mt)
#pragma unroll
      for (int qn = 0; qn < 4; ++qn) {
        f32x4 s = mfma16(kf[mt][0], qf[qn][0], zero);
        sacc[mt][qn] = mfma16(kf[mt][1], qf[qn][1], s);
      }
    bf16x8 vf[4];
#pragma unroll
    for (int dt = 0; dt < 4; ++dt) vf[dt] = ld_bf8(Vt + vidx + dt * 32768 + kb);
    f32x4 km[2];
    km[0] = *(const f32x4*)(kmask + kmi + kb);
    km[1] = *(const f32x4*)(kmask + kmi + kb + 16);
#pragma unroll
    for (int mt = 0; mt < 2; ++mt)
#pragma unroll
      for (int qn = 0; qn < 4; ++qn) {
        f32x4 p;
#pragma unroll
        for (int r = 0; r < 4; ++r) p[r] = EXP2F(sacc[mt][qn][r]) * km[mt][r];
        lpart[qn] += p[0] + p[1] + p[2] + p[3];
        *(uint2*)(pw + qn * 640 + pbase + mt * 16) =
            make_uint2(pk2(p[0], p[1]), pk2(p[2], p[3]));
      }
    bf16x8 pf[4];
#pragma unroll
    for (int qn = 0; qn < 4; ++qn) pf[qn] = ld_bf8(pw + qn * 640 + prd);
    int nkb = ((it + 1) & 15) << 7;
    bf16x8 nkf[2][2];
#pragma unroll
    for (int mt = 0; mt < 2; ++mt) {
      nkf[mt][0] = ld_bf8(Kb + kidx + nkb * 512 + mt * 8192);
      nkf[mt][1] = ld_bf8(Kb + kidx + nkb * 512 + mt * 8192 + 32);
    }
#pragma unroll
    for (int dt = 0; dt < 4; ++dt)
#pragma unroll
      for (int qn = 0; qn < 4; ++qn)
        oacc[dt][qn] = mfma16(vf[dt], pf[qn], oacc[dt][qn]);
#pragma unroll
    for (int mt = 0; mt < 2; ++mt) {
      kf[mt][0] = nkf[mt][0];
      kf[mt][1] = nkf[mt][1];
    }
  }

#pragma unroll
  for (int qn = 0; qn < 4; ++qn) {
    lpart[qn] += __shfl_xor(lpart[qn], 16);
    lpart[qn] += __shfl_xor(lpart[qn], 32);
  }
  if (quad == 0) {
#pragma unroll
    for (int qn = 0; qn < 4; ++qn) lbuf[w][qn * 16 + mrow] = lpart[qn];
  }
  __syncthreads();

  for (int ph = 0; ph < 4; ++ph) {
    if (w == ph) {
#pragma unroll
      for (int dt = 0; dt < 4; ++dt)
#pragma unroll
        for (int qn = 0; qn < 4; ++qn) {
          float* dst = Obuf + (qn * 16 + mrow) * 68 + dt * 16 + quad * 4;
          f32x4 v = oacc[dt][qn];
          if (ph) {
            v[0] += dst[0]; v[1] += dst[1]; v[2] += dst[2]; v[3] += dst[3];
          }
          dst[0] = v[0]; dst[1] = v[1]; dst[2] = v[2]; dst[3] = v[3];
        }
    }
    __syncthreads();
  }

#pragma unroll
  for (int i = 0; i < 4; ++i) {
    int qr = w * 16 + i * 4 + quad;
    float l = lbuf[0][qr] + lbuf[1][qr] + lbuf[2][qr] + lbuf[3][qr];
    int qg = b * 2048 + q0 + qr;
    float inv = qmask[qg] / l;
    const float* ob = Obuf + qr * 68 + mrow * 4;
    const float4 res = *(const float4*)(queries + qg * 512 + h * 64 + mrow * 4);
    float4 r;
    r.x = ob[0] * inv + res.x;
    r.y = ob[1] * inv + res.y;
    r.z = ob[2] * inv + res.z;
    r.w = ob[3] * inv + res.w;
    *(float4*)(out + qg * 512 + h * 64 + mrow * 4) = r;
  }
}

// ---------------------------------------------------------------------------
// Kernel 5: LayerNorm (unbiased std, eps added to std), in-place on d_out.
// ---------------------------------------------------------------------------
__global__ __launch_bounds__(256) void ln_kernel(float* __restrict__ out,
                                                 const float* __restrict__ gamma,
                                                 const float* __restrict__ beta) {
  int row = blockIdx.x * 4 + (threadIdx.x >> 6);
  int lane = threadIdx.x & 63;
  float* p = out + row * 512;
  float4 v1 = ((const float4*)p)[lane];
  float4 v2 = ((const float4*)p)[64 + lane];
  float s = v1.x + v1.y + v1.z + v1.w + v2.x + v2.y + v2.z + v2.w;
  float sq = v1.x * v1.x + v1.y * v1.y + v1.z * v1.z + v1.w * v1.w +
             v2.x * v2.x + v2.y * v2.y + v2.z * v2.z + v2.w * v2.w;
#pragma unroll
  for (int off = 32; off > 0; off >>= 1) {
    s += __shfl_xor(s, off);
    sq += __shfl_xor(sq, off);
  }
  float mean = s * (1.f / 512.f);
  float var = fmaxf((sq - 512.f * mean * mean) * (1.f / 511.f), 0.f);
  float inv = 1.f / (sqrtf(var) + 1e-8f);
  float4 g1 = ((const float4*)gamma)[lane];
  float4 g2 = ((const float4*)gamma)[64 + lane];
  float4 b1 = ((const float4*)beta)[lane];
  float4 b2 = ((const float4*)beta)[64 + lane];
  v1.x = g1.x * (v1.x - mean) * inv + b1.x;
  v1.y = g1.y * (v1.y - mean) * inv + b1.y;
  v1.z = g1.z * (v1.z - mean) * inv + b1.z;
  v1.w = g1.w * (v1.w - mean) * inv + b1.w;
  v2.x = g2.x * (v2.x - mean) * inv + b2.x;
  v2.y = g2.y * (v2.y - mean) * inv + b2.y;
  v2.z = g2.z * (v2.z - mean) * inv + b2.z;
  v2.w = g2.w * (v2.w - mean) * inv + b2.w;
  ((float4*)p)[lane] = v1;
  ((float4*)p)[64 + lane] = v2;
}

// ---------------------------------------------------------------------------
extern "C" void kernel_launch(void* const* d_in, const int* in_sizes, int n_in,
                              void* d_out, int out_size, void* d_ws, size_t ws_size,
                              hipStream_t stream) {
  (void)in_sizes; (void)n_in; (void)out_size; (void)ws_size;
  const float* queries = (const float*)d_in[0];
  const float* keys    = (const float*)d_in[1];
  const float* values  = (const float*)d_in[2];
  const float* Wq = (const float*)d_in[3];
  const float* bq = (const float*)d_in[4];
  const float* Wk = (const float*)d_in[5];
  const float* bk = (const float*)d_in[6];
  const float* Wv = (const float*)d_in[7];
  const float* bv = (const float*)d_in[8];
  const float* gamma = (const float*)d_in[9];
  const float* beta  = (const float*)d_in[10];
  float* out = (float*)d_out;

  char* ws = (char*)d_ws;
  unsigned short* Qb = (unsigned short*)(ws);                    // 8 MB
  unsigned short* Kb = (unsigned short*)(ws + 8 * 1024 * 1024);  // 8 MB
  unsigned short* Vt = (unsigned short*)(ws + 16 * 1024 * 1024); // 8 MB  [32][64][2048]
  unsigned short* Wt = (unsigned short*)(ws + 24 * 1024 * 1024); // 1.5 MB
  float* qmask = (float*)(ws + 24 * 1024 * 1024 + 3 * 512 * 512 * 2);
  float* kmask = qmask + 8192;

  wt_kernel<<<384, 256, 0, stream>>>(Wq, Wk, Wv, Wt);
  mask_kernel<<<4096, 256, 0, stream>>>(queries, keys, qmask, kmask);
  proj_kernel<<<dim3(192, 4), 256, 0, stream>>>(queries, keys, values, bq, bk, bv,
                                                Wt, Qb, Kb, Vt);
  attn_kernel<<<dim3(32, 32), 256, 0, stream>>>(Qb, Kb, Vt, qmask, kmask, queries, out);
  ln_kernel<<<2048, 256, 0, stream>>>(out, gamma, beta);
}